// Round 5
// baseline (212.119 us; speedup 1.0000x reference)
//
#include <hip/hip_runtime.h>
#include <stdint.h>

#define BATCH 32
#define IMG 512
#define CH 3
#define GOUT 64
#define ROWB (IMG*CH)   // 1536 floats per image row
#define GP   ((size_t)BATCH*CH*GOUT*IMG)   // planar g (single, no K-split)

typedef __attribute__((ext_vector_type(8))) short          short8;   // 8 bf16
typedef __attribute__((ext_vector_type(8))) unsigned short ushort8;
typedef __attribute__((ext_vector_type(4))) float          floatx4;  // MFMA acc
typedef __attribute__((ext_vector_type(4))) float          floatv4;

__device__ __forceinline__ unsigned short f2bf(float x) {
    unsigned u = __builtin_bit_cast(unsigned, x);
    u += 0x7FFFu + ((u >> 16) & 1u);
    return (unsigned short)(u >> 16);
}

// ---------------------------------------------------------------------------
// Kernel 1: Gaussian filterbank masks, TRANSPOSED bf16: AyT[b][H][h],
// AxT[b][W][w] (k-contiguous). One wave per (b, axis, r). (unchanged, verified)
// ---------------------------------------------------------------------------
__global__ __launch_bounds__(64) void mask_kernel(const float* __restrict__ tp,
                                                  unsigned short* __restrict__ AyT,
                                                  unsigned short* __restrict__ AxT) {
    int blk  = blockIdx.x;
    int r    = blk & 63;
    int axis = (blk >> 6) & 1;
    int b    = blk >> 7;

    const float* p = tp + b*6 + (axis ? 3 : 0);
    float u = p[0], s = p[1], d = p[2];
    float centre = u + (float)r * d;
    float inv_s  = 1.0f / s;

    int lane = threadIdx.x;
    float e[8];
    float sum = 0.0f;
    #pragma unroll
    for (int i = 0; i < 8; ++i) {
        float z = ((float)(i*64 + lane) - centre) * inv_s;
        e[i] = __expf(-0.5f * z * z);
        sum += e[i];
    }
    #pragma unroll
    for (int m = 1; m < 64; m <<= 1)
        sum += __shfl_xor(sum, m, 64);
    float inv_sum = 1.0f / (sum + 1e-8f);

    unsigned short* dst = (axis ? AxT : AyT) + ((size_t)b*GOUT + r) * IMG;
    #pragma unroll
    for (int i = 0; i < 8; ++i)
        dst[i*64 + lane] = f2bf(e[i] * inv_sum);
}

// ---------------------------------------------------------------------------
// Kernel T: img fp32 [b][h][wc] -> imgT bf16 [b][wc][h].
// Round-10 rationale: 4 structurally different stage1s all pinned at
// ~1.3 TB/s because (a) their img reads are 256B-granule at 6KB stride
// (DRAM row-activate per 256B) and (b) the first kernel after the 384MiB
// poison fill runs under its L3->HBM writeback drain. This kernel touches
// HBM exactly ONCE, contiguously (1KB/wave-instr runs, m13-proven pattern),
// and leaves compact k(=h)-contiguous bf16 in L3 for the MFMA kernels.
// 32h x 256wc tiles via LDS: dense b128 writes, dense row reads - no
// conflicts by construction. Grid 3072, 32KB LDS -> 5 blocks/CU.
// ---------------------------------------------------------------------------
__global__ __launch_bounds__(256) void transpose_kernel(const float* __restrict__ img,
                                                        unsigned short* __restrict__ imgT) {
    __shared__ float Ls[32][256];   // [h_local][wc_local]

    int blk = blockIdx.x;
    int wt  = blk % 6;
    int hs  = (blk / 6) % 16;
    int b   = blk / 96;
    int h0  = hs * 32;
    int wc0 = wt * 256;
    int t   = threadIdx.x;

    // read: 8 rounds x 4 rows; each wave-instr = 64 lanes x 16B = 1KB run.
    const float* src = img + ((size_t)(b*IMG + h0 + (t >> 6)) * ROWB + wc0 + (t & 63)*4);
    #pragma unroll
    for (int rnd = 0; rnd < 8; ++rnd) {
        floatv4 v = *(const floatv4*)(src + (size_t)rnd*4*ROWB);
        *(floatv4*)&Ls[rnd*4 + (t >> 6)][(t & 63)*4] = v;   // dense b128, aligned
    }
    __syncthreads();

    // write: thread t owns wc_local = t; LDS row reads are lane-dense
    // (conflict-free); output 16B/lane at 1KB stride (L2/L3-absorbed).
    unsigned short* dst = imgT + ((size_t)(b*ROWB + wc0 + t)) * IMG + h0;
    #pragma unroll
    for (int seg = 0; seg < 4; ++seg) {
        ushort8 o;
        #pragma unroll
        for (int j = 0; j < 8; ++j)
            o[j] = f2bf(Ls[seg*8 + j][t]);
        *(ushort8*)(dst + seg*8) = o;
    }
}

// ---------------------------------------------------------------------------
// Kernel 2: gP[b][c][H][w] = sum_h Ay[b,h,H]*img[b,h,w,c]
// Round-10: NO LDS, NO barriers, NO K-split. Both MFMA fragments are 16B
// k-contiguous loads: B from imgT (L3-hot), A from AyT (L2-hot). Register
// pipelined (unroll 4); grid 768 (3 blocks/CU), full K=512 per block.
// ---------------------------------------------------------------------------
__global__ __launch_bounds__(256, 4) void stage1_kernel(const unsigned short* __restrict__ imgT,
                                                        const unsigned short* __restrict__ AyT,
                                                        float* __restrict__ gP) {
    int tile = blockIdx.x % 24;
    int b    = blockIdx.x / 24;
    int wc0  = tile * 64;
    int tid  = threadIdx.x;
    int wave = tid >> 6;
    int lane = tid & 63;
    int n16  = lane & 15;
    int q    = lane >> 4;

    floatx4 acc[4];
    #pragma unroll
    for (int mt = 0; mt < 4; ++mt) acc[mt] = (floatx4){0.f, 0.f, 0.f, 0.f};

    // this lane's wc row of imgT (k=h contiguous)
    const unsigned short* imt = imgT + ((size_t)b*ROWB + wc0 + wave*16 + n16) * IMG;
    const unsigned short* ayb = AyT + (size_t)b * GOUT * IMG;

    #pragma unroll 4
    for (int kk = 0; kk < 16; ++kk) {
        int hk = kk*32 + q*8;
        short8 bf = *(const short8*)(imt + hk);
        #pragma unroll
        for (int mt = 0; mt < 4; ++mt) {
            short8 af = *(const short8*)(ayb + (size_t)(mt*16 + n16) * IMG + hk);
            acc[mt] = __builtin_amdgcn_mfma_f32_16x16x32_bf16(af, bf, acc[mt], 0, 0, 0);
        }
    }

    // Epilogue: D col = lane&15 -> wc, row = q*4+reg -> H (verified r4/r5).
    int wc = wc0 + wave*16 + n16;
    int c = wc % 3, w = wc / 3;
    float* gb = gP + ((size_t)(b*CH + c) * GOUT) * IMG + w;
    #pragma unroll
    for (int mt = 0; mt < 4; ++mt)
        #pragma unroll
        for (int reg = 0; reg < 4; ++reg)
            gb[(size_t)(mt*16 + q*4 + reg) * IMG] = acc[mt][reg];
}

// ---------------------------------------------------------------------------
// Kernel 3: out[b,H,W,c] += sum_{w in part} g[b,c,H,w] * Ax[b,w,W]
// r3 structure (K-split 2, register prefetch, 2-way atomics), single gP.
// ---------------------------------------------------------------------------
__global__ __launch_bounds__(256, 4) void stage2_kernel(const float* __restrict__ gP,
                                                        const unsigned short* __restrict__ AxT,
                                                        float* __restrict__ out) {
    int blk  = blockIdx.x;
    int part = blk & 1;
    int hq   = (blk >> 1) & 3;    // H-quadrant (16 rows)
    int bc   = blk >> 3;
    int c    = bc % 3;
    int b    = bc / 3;
    int tid  = threadIdx.x;
    int wq   = tid >> 6;          // owns W-tile wq*16..+15
    int lane = tid & 63;
    int n16  = lane & 15;
    int q    = lane >> 4;

    floatx4 acc = (floatx4){0.f, 0.f, 0.f, 0.f};

    const float*          ga  = gP  + ((size_t)(b*CH + c) * GOUT + hq*16 + n16) * IMG;
    const unsigned short* axb = AxT + ((size_t)b*GOUT + wq*16 + n16) * IMG;

    #pragma unroll
    for (int ph = 0; ph < 2; ++ph) {
        floatv4 A0[4], A1[4];
        short8  BF[4];
        #pragma unroll
        for (int cc = 0; cc < 4; ++cc) {
            int w0 = part*256 + ph*128 + cc*32 + q*8;
            A0[cc] = *(const floatv4*)(ga + w0);
            A1[cc] = *(const floatv4*)(ga + w0 + 4);
            BF[cc] = *(const short8*)(axb + w0);
        }
        #pragma unroll
        for (int cc = 0; cc < 4; ++cc) {
            short8 af;
            af[0] = (short)f2bf(A0[cc][0]);
            af[1] = (short)f2bf(A0[cc][1]);
            af[2] = (short)f2bf(A0[cc][2]);
            af[3] = (short)f2bf(A0[cc][3]);
            af[4] = (short)f2bf(A1[cc][0]);
            af[5] = (short)f2bf(A1[cc][1]);
            af[6] = (short)f2bf(A1[cc][2]);
            af[7] = (short)f2bf(A1[cc][3]);
            acc = __builtin_amdgcn_mfma_f32_16x16x32_bf16(af, BF[cc], acc, 0, 0, 0);
        }
    }

    float* ob = out + (((size_t)b*GOUT + hq*16) * GOUT + wq*16 + n16) * CH + c;
    #pragma unroll
    for (int reg = 0; reg < 4; ++reg)
        atomicAdd(ob + (size_t)(q*4 + reg) * GOUT * CH, acc[reg]);
}

// ---------------------------------------------------------------------------
// Workspace: AyT 2MB | AxT 2MB | imgT 50.3MB | gP 12.6MB  (~67 MB).
// ---------------------------------------------------------------------------
extern "C" void kernel_launch(void* const* d_in, const int* in_sizes, int n_in,
                              void* d_out, int out_size, void* d_ws, size_t ws_size,
                              hipStream_t stream) {
    const float* img = (const float*)d_in[0];
    const float* tp  = (const float*)d_in[1];
    float* out = (float*)d_out;

    unsigned short* AyT  = (unsigned short*)d_ws;
    unsigned short* AxT  = AyT + (size_t)BATCH * GOUT * IMG;
    unsigned short* imgT = AxT + (size_t)BATCH * GOUT * IMG;
    float*          gPp  = (float*)(imgT + (size_t)BATCH * ROWB * IMG);

    hipMemsetAsync(d_out, 0, (size_t)out_size * sizeof(float), stream);
    transpose_kernel<<<BATCH * 16 * 6,     256, 0, stream>>>(img, imgT);
    mask_kernel     <<<BATCH * 2 * GOUT,    64, 0, stream>>>(tp, AyT, AxT);
    stage1_kernel   <<<BATCH * 24,         256, 0, stream>>>(imgT, AyT, gPp);
    stage2_kernel   <<<BATCH * CH * 4 * 2, 256, 0, stream>>>(gPp, AxT, out);
}

// Round 6
// 185.292 us; speedup vs baseline: 1.1448x; 1.1448x over previous
//
#include <hip/hip_runtime.h>
#include <stdint.h>

#define BATCH 32
#define IMG 512
#define CH 3
#define GOUT 64
#define ROWB (IMG*CH)   // 1536 floats per image row
#define GP   ((size_t)BATCH*CH*GOUT*IMG)   // one K-split partial of planar g

typedef __attribute__((ext_vector_type(8))) short  short8;   // 8 bf16 = 4 VGPRs
typedef __attribute__((ext_vector_type(4))) float  floatx4;  // MFMA 16x16 acc

__device__ __forceinline__ unsigned short f2bf(float x) {
    unsigned u = __builtin_bit_cast(unsigned, x);
    u += 0x7FFFu + ((u >> 16) & 1u);
    return (unsigned short)(u >> 16);
}

// CK-style async global->LDS 16B copy. LDS dest must be wave-uniform base +
// lane*16 (caller guarantees via layout). Flat->as3 via uintptr truncation
// keeps the LDS offset (shared aperture holds offset in low bits).
typedef __attribute__((address_space(3))) unsigned int  lds_u32;
typedef __attribute__((address_space(1))) const unsigned int g_u32;
__device__ __forceinline__ void async16(const void* g, void* l) {
    __builtin_amdgcn_global_load_lds((g_u32*)(uintptr_t)g,
                                     (lds_u32*)(uintptr_t)l, 16, 0, 0);
}

// ---------------------------------------------------------------------------
// SESSION MODEL (r0-r5): dur_us = 118.8us harness re-poison fills (2 x 384MiB
// fillBufferAligned inside the timed window, not addressable) + ~58us for
// whichever kernel reads img first (pinned by the fills' L3->HBM writeback
// drain: 5 structurally different img-readers all measured 55-67us, incl. a
// pure-streaming transpose) + ~9us tail (mask + stage2 + gaps). This r0
// structure does ALL img reading and the full stage-1 contraction inside the
// drain shadow (pipes are ~95% idle there; the MFMA work is free), keeping
// everything else tiny. Measured 185.9/186.3us = the structural floor.
// ---------------------------------------------------------------------------

// ---------------------------------------------------------------------------
// Kernel 1: Gaussian filterbank masks, TRANSPOSED bf16: AyT[b][H][h],
// AxT[b][W][w] (k-contiguous). One wave per (b, axis, r).
// ---------------------------------------------------------------------------
__global__ __launch_bounds__(64) void mask_kernel(const float* __restrict__ tp,
                                                  unsigned short* __restrict__ AyT,
                                                  unsigned short* __restrict__ AxT) {
    int blk  = blockIdx.x;
    int r    = blk & 63;
    int axis = (blk >> 6) & 1;
    int b    = blk >> 7;

    const float* p = tp + b*6 + (axis ? 3 : 0);
    float u = p[0], s = p[1], d = p[2];
    float centre = u + (float)r * d;
    float inv_s  = 1.0f / s;

    int lane = threadIdx.x;
    float e[8];
    float sum = 0.0f;
    #pragma unroll
    for (int i = 0; i < 8; ++i) {
        float z = ((float)(i*64 + lane) - centre) * inv_s;
        e[i] = __expf(-0.5f * z * z);
        sum += e[i];
    }
    #pragma unroll
    for (int m = 1; m < 64; m <<= 1)
        sum += __shfl_xor(sum, m, 64);
    float inv_sum = 1.0f / (sum + 1e-8f);

    unsigned short* dst = (axis ? AxT : AyT) + ((size_t)b*GOUT + r) * IMG;
    #pragma unroll
    for (int i = 0; i < 8; ++i)
        dst[i*64 + lane] = f2bf(e[i] * inv_sum);
}

// ---------------------------------------------------------------------------
// Kernel 2: gP[part][b][c][H][w] = sum_{h in part} Ay[b,h,H]*img[b,h,w,c]
// 64H x 64wc tile, BK=64, K-split 2 -> 1536 blocks, LDS 25.6 KB ->
// 6 blocks/CU = 24 waves/CU. Bs staged by global_load_lds width=16 (async,
// no VGPR round-trip); As (bf16, +8 pad) staged normally. 4 waves each own a
// 16-wc strip; 8 MFMA/chunk/wave. Runs inside the poison-fill drain shadow;
// its ~58us is the drain window, not this code (r1-r5 ablations).
// ---------------------------------------------------------------------------
__global__ __launch_bounds__(256, 6) void stage1_kernel(const float* __restrict__ img,
                                                        const unsigned short* __restrict__ AyT,
                                                        float* __restrict__ gP) {
    __shared__ float          Bs[64][64];   // img tile fp32, UNPADDED (async dest)
    __shared__ unsigned short As[64][72];   // Ay tile bf16, +8 pad

    int part = blockIdx.x & 1;
    int bt   = blockIdx.x >> 1;
    int tile = bt % 24;
    int b    = bt / 24;
    int wc0  = tile * 64;
    int tid  = threadIdx.x;
    int wave = tid >> 6;
    int lane = tid & 63;
    int n16  = lane & 15;
    int q    = lane >> 4;

    floatx4 acc[4];
    #pragma unroll
    for (int mt = 0; mt < 4; ++mt) acc[mt] = (floatx4){0.f, 0.f, 0.f, 0.f};

    const float*          imb = img + (size_t)b * IMG * ROWB + wc0;
    const unsigned short* ayb = AyT + (size_t)b * GOUT * IMG;

    int rb = (tid >> 6)*4 + ((tid & 63) >> 4);  // async row base (w*4 + l>>4)
    int cg = tid & 15;                          // float4 within row

    for (int h0 = part*256; h0 < part*256 + 256; h0 += 64) {
        // --- As loads first (so their waitcnt doesn't drain Bs queue) ---
        uint4 av[2];
        #pragma unroll
        for (int i = 0; i < 2; ++i) {
            int p = tid + i*256;
            av[i] = *(const uint4*)(ayb + (size_t)(p >> 3) * IMG + h0 + (p & 7)*8);
        }
        // --- Bs: async global->LDS, 4 instrs/wave, 1 KB contiguous each ---
        #pragma unroll
        for (int i = 0; i < 4; ++i) {
            int r = rb + i*16;
            async16(imb + (size_t)(h0 + r) * ROWB + cg*4, &Bs[r][cg*4]);
        }
        #pragma unroll
        for (int i = 0; i < 2; ++i) {
            int p = tid + i*256;
            *(uint4*)&As[p >> 3][(p & 7)*8] = av[i];
        }
        __syncthreads();   // drains vmcnt (incl. async) + lgkm

        #pragma unroll
        for (int s = 0; s < 2; ++s) {
            short8 bf;
            #pragma unroll
            for (int j = 0; j < 8; ++j)
                bf[j] = (short)f2bf(Bs[s*32 + q*8 + j][wave*16 + n16]);
            #pragma unroll
            for (int mt = 0; mt < 4; ++mt) {
                short8 af = *(const short8*)&As[mt*16 + n16][s*32 + q*8];
                acc[mt] = __builtin_amdgcn_mfma_f32_16x16x32_bf16(af, bf, acc[mt], 0, 0, 0);
            }
        }
        __syncthreads();
    }

    // Epilogue: D col = lane&15 -> wc, row = q*4+reg -> H (verified r4/r5).
    int wc = wc0 + wave*16 + n16;
    int c = wc % 3, w = wc / 3;
    float* gb = gP + (size_t)part * GP + ((size_t)(b*CH + c) * GOUT) * IMG + w;
    #pragma unroll
    for (int mt = 0; mt < 4; ++mt)
        #pragma unroll
        for (int reg = 0; reg < 4; ++reg)
            gb[(size_t)(mt*16 + q*4 + reg) * IMG] = acc[mt][reg];
}

// ---------------------------------------------------------------------------
// Kernel 3: out[b,H,W,c] += sum_{w part} (g0+g1)[b,c,H,w] * Ax[b,w,W]
// bf16 MFMA; grid (b,c,part)=384; K-split 4, fp32 atomicAdd into zeroed out.
// ---------------------------------------------------------------------------
__global__ __launch_bounds__(256) void stage2_kernel(const float* __restrict__ gP,
                                                     const unsigned short* __restrict__ AxT,
                                                     float* __restrict__ out) {
    int blk  = blockIdx.x;
    int part = blk & 3;
    int bc   = blk >> 2;
    int c    = bc % 3;
    int b    = bc / 3;
    int tid  = threadIdx.x;
    int wm   = tid >> 6;
    int lane = tid & 63;
    int n16  = lane & 15;
    int q    = lane >> 4;

    floatx4 acc[4];
    #pragma unroll
    for (int nt = 0; nt < 4; ++nt) acc[nt] = (floatx4){0.f, 0.f, 0.f, 0.f};

    const float*          ga  = gP  + ((size_t)(b*CH + c) * GOUT + wm*16 + n16) * IMG;
    const unsigned short* axb = AxT + ((size_t)b*GOUT + n16) * IMG;

    #pragma unroll
    for (int cc = 0; cc < 4; ++cc) {
        int w0 = part*128 + cc*32;
        const float* ap = ga + w0 + q*8;
        float4 a0 = *(const float4*)ap;
        float4 a1 = *(const float4*)(ap + 4);
        float4 b0 = *(const float4*)(ap + GP);
        float4 b1 = *(const float4*)(ap + GP + 4);
        short8 af;
        af[0] = (short)f2bf(a0.x + b0.x); af[1] = (short)f2bf(a0.y + b0.y);
        af[2] = (short)f2bf(a0.z + b0.z); af[3] = (short)f2bf(a0.w + b0.w);
        af[4] = (short)f2bf(a1.x + b1.x); af[5] = (short)f2bf(a1.y + b1.y);
        af[6] = (short)f2bf(a1.z + b1.z); af[7] = (short)f2bf(a1.w + b1.w);

        #pragma unroll
        for (int nt = 0; nt < 4; ++nt) {
            short8 bf = *(const short8*)(axb + (size_t)nt*16*IMG + w0 + q*8);
            acc[nt] = __builtin_amdgcn_mfma_f32_16x16x32_bf16(af, bf, acc[nt], 0, 0, 0);
        }
    }

    #pragma unroll
    for (int nt = 0; nt < 4; ++nt) {
        int W = nt*16 + n16;
        #pragma unroll
        for (int reg = 0; reg < 4; ++reg) {
            int H = wm*16 + q*4 + reg;
            atomicAdd(out + (((size_t)b*GOUT + H) * GOUT + W) * CH + c, acc[nt][reg]);
        }
    }
}

// ---------------------------------------------------------------------------
// Workspace: AyT 2 MB | AxT 2 MB | gP 2 x 12.6 MB  (~29 MB).
// ---------------------------------------------------------------------------
extern "C" void kernel_launch(void* const* d_in, const int* in_sizes, int n_in,
                              void* d_out, int out_size, void* d_ws, size_t ws_size,
                              hipStream_t stream) {
    const float* img = (const float*)d_in[0];
    const float* tp  = (const float*)d_in[1];
    float* out = (float*)d_out;

    unsigned short* AyT = (unsigned short*)d_ws;
    unsigned short* AxT = AyT + (size_t)BATCH * GOUT * IMG;
    float*          gPp = (float*)(AxT + (size_t)BATCH * GOUT * IMG);

    hipMemsetAsync(d_out, 0, (size_t)out_size * sizeof(float), stream);
    mask_kernel  <<<BATCH * 2 * GOUT,   64, 0, stream>>>(tp, AyT, AxT);
    stage1_kernel<<<BATCH * 24 * 2,    256, 0, stream>>>(img, AyT, gPp);
    stage2_kernel<<<BATCH * CH * 4,    256, 0, stream>>>(gPp, AxT, out);
}